// Round 6
// baseline (86.937 us; speedup 1.0000x reference)
//
#include <hip/hip_runtime.h>

// AffineExponential: y = expm(t*W) @ x + bias*t,  ljd = diag(W)*t
//
// Round-5 restructure: expm(tW) = sum_k t^k G_k with G_k = W^k/k! a FIXED
// matrix set -> precompute G_k once (kernel 1, 8 blocks, row-slice parallel:
// G_k[I,:] = G_{k-1}[I,:]*W/k needs only rows I), then kernel 2 is a pure
// barrier-free GEMM: y_b = x_b + sum_k G_k (t_b^k x_b), t^k folded into the
// f16 B-fragment by one v_pk_mul_f16 sweep per k, MFMAs chain straight into
// the y accumulator. Kills the per-k LDS round trip + barrier + per-block
// W-conversion startup that limited rounds 3-5.
// Precision: G,W in f16 hi+lo split (~fp32); X in f16 (2^-11 < bf16 2^-8).
// K=10: ||tW|| <= ~2.2 -> tail ~1.5e-4.

#define DD 128
#define KT 10

typedef float f32x4 __attribute__((ext_vector_type(4)));
typedef _Float16 f16x8 __attribute__((ext_vector_type(8)));

// ws fragment layout: frag(k,r,kf,hl) at ((((k-1)*8+r)*4+kf)*2+hl)*512 halves,
// lane l owns halves [l*8, l*8+8). A-frag: A[m=lane&15][kd=32*kf+(lane>>4)*8+j].

__global__ __launch_bounds__(256, 1)
void gpow_kernel(const float* __restrict__ weight, _Float16* __restrict__ gws)
{
    __shared__ float wlds[DD * DD];          // 64 KB, W row-major
    __shared__ float gbuf[2][16 * 132];      // 16 rows x 128 cols fp32, pad 132

    const int tid = threadIdx.x;
    const int w = tid >> 6, l = tid & 63, n = l & 15, q = l >> 4;
    const int r = blockIdx.x;                // rows [16r, 16r+16)

    for (int i = tid; i < DD * DD / 4; i += 256)
        reinterpret_cast<f32x4*>(wlds)[i] = reinterpret_cast<const f32x4*>(weight)[i];
    __syncthreads();

    // B-frags of W (hi/lo f16): B[kd=32kf+q*8+j][col=32w+16ct+n]
    f16x8 Bh[2][4], Bl[2][4];
#pragma unroll
    for (int ct = 0; ct < 2; ++ct)
#pragma unroll
        for (int kf = 0; kf < 4; ++kf)
#pragma unroll
            for (int j = 0; j < 8; ++j) {
                const float f = wlds[(32 * kf + q * 8 + j) * DD + 32 * w + 16 * ct + n];
                const _Float16 h = (_Float16)f;
                Bh[ct][kf][j] = h;
                Bl[ct][kf][j] = (_Float16)(f - (float)h);
            }

    // A-frags of G_1 = W rows [16r, 16r+16)
    f16x8 Ah[4], Al[4];
#pragma unroll
    for (int kf = 0; kf < 4; ++kf) {
        const float* p = wlds + (16 * r + n) * DD + 32 * kf + q * 8;
#pragma unroll
        for (int j = 0; j < 8; ++j) {
            const float f = p[j];
            const _Float16 h = (_Float16)f;
            Ah[kf][j] = h;
            Al[kf][j] = (_Float16)(f - (float)h);
        }
    }

#define STORE_FRAGS(kk)                                                              \
    {                                                                                \
        _Pragma("unroll")                                                            \
        for (int kf = 0; kf < 4; ++kf)                                               \
            if (kf == w) {                                                           \
                size_t o0 = ((size_t)(((((kk)-1) * 8 + r) * 4 + kf) * 2 + 0)) * 512 + l * 8; \
                size_t o1 = ((size_t)(((((kk)-1) * 8 + r) * 4 + kf) * 2 + 1)) * 512 + l * 8; \
                *reinterpret_cast<f16x8*>(gws + o0) = Ah[kf];                        \
                *reinterpret_cast<f16x8*>(gws + o1) = Al[kf];                        \
            }                                                                        \
    }

    STORE_FRAGS(1);

    int cur = 0;
#pragma unroll 1
    for (int k = 2; k <= KT; ++k) {
        f32x4 C0 = {0.f, 0.f, 0.f, 0.f}, C1 = {0.f, 0.f, 0.f, 0.f};
#pragma unroll
        for (int kf = 0; kf < 4; ++kf) {
            C0 = __builtin_amdgcn_mfma_f32_16x16x32_f16(Ah[kf], Bh[0][kf], C0, 0, 0, 0);
            C0 = __builtin_amdgcn_mfma_f32_16x16x32_f16(Al[kf], Bh[0][kf], C0, 0, 0, 0);
            C0 = __builtin_amdgcn_mfma_f32_16x16x32_f16(Ah[kf], Bl[0][kf], C0, 0, 0, 0);
            C1 = __builtin_amdgcn_mfma_f32_16x16x32_f16(Ah[kf], Bh[1][kf], C1, 0, 0, 0);
            C1 = __builtin_amdgcn_mfma_f32_16x16x32_f16(Al[kf], Bh[1][kf], C1, 0, 0, 0);
            C1 = __builtin_amdgcn_mfma_f32_16x16x32_f16(Ah[kf], Bl[1][kf], C1, 0, 0, 0);
        }
        const float inv = 1.0f / (float)k;
        C0 *= inv;
        C1 *= inv;
        // C layout: col = lane&15 (global 32w+16ct+n), row = q*4+reg
#pragma unroll
        for (int jr = 0; jr < 4; ++jr) {
            gbuf[cur][(q * 4 + jr) * 132 + 32 * w + n]      = C0[jr];
            gbuf[cur][(q * 4 + jr) * 132 + 32 * w + 16 + n] = C1[jr];
        }
        __syncthreads();
        // rebuild A-frags (row m = n) + hi/lo split
#pragma unroll
        for (int kf = 0; kf < 4; ++kf) {
            const float* p = &gbuf[cur][n * 132 + 32 * kf + q * 8];
            const f32x4 a = *reinterpret_cast<const f32x4*>(p);
            const f32x4 b = *reinterpret_cast<const f32x4*>(p + 4);
#pragma unroll
            for (int j = 0; j < 4; ++j) {
                const _Float16 h0 = (_Float16)a[j];
                const _Float16 h1 = (_Float16)b[j];
                Ah[kf][j]     = h0;
                Ah[kf][j + 4] = h1;
                Al[kf][j]     = (_Float16)(a[j] - (float)h0);
                Al[kf][j + 4] = (_Float16)(b[j] - (float)h1);
            }
        }
        STORE_FRAGS(k);
        cur ^= 1;
    }
}

__global__ __launch_bounds__(256, 1)
void apply_kernel(const float* __restrict__ x,
                  const float* __restrict__ t,
                  const float* __restrict__ weight,
                  const float* __restrict__ bias,
                  const _Float16* __restrict__ gws,
                  float* __restrict__ out, int B)
{
    const int tid = threadIdx.x;
    const int w = tid >> 6, l = tid & 63, n = l & 15, q = l >> 4;
    const int s0 = blockIdx.x * 16;

    const float tn = t[s0 + n];
    const _Float16 th = (_Float16)tn;
    f16x8 tv;
#pragma unroll
    for (int j = 0; j < 8; ++j) tv[j] = th;

    // X column fragments (f16): xf[kf][j] = x[s0+n][32kf + q*8 + j]
    f16x8 xf[4];
    const float* xp = x + (size_t)(s0 + n) * DD + q * 8;
#pragma unroll
    for (int kf = 0; kf < 4; ++kf) {
        const f32x4 a = *reinterpret_cast<const f32x4*>(xp + 32 * kf);
        const f32x4 b = *reinterpret_cast<const f32x4*>(xp + 32 * kf + 4);
#pragma unroll
        for (int j = 0; j < 4; ++j) {
            xf[kf][j]     = (_Float16)a[j];
            xf[kf][j + 4] = (_Float16)b[j];
        }
    }

    // y accumulators in C layout (col = n, rows g0..g0+3 / +16); init = x (k=0)
    const int g0 = w * 32 + q * 4;
    f32x4 y0a = *reinterpret_cast<const f32x4*>(x + (size_t)(s0 + n) * DD + g0);
    f32x4 y1a = *reinterpret_cast<const f32x4*>(x + (size_t)(s0 + n) * DD + g0 + 16);
    f32x4 y0b = {0.f, 0.f, 0.f, 0.f};
    f32x4 y1b = {0.f, 0.f, 0.f, 0.f};

    const int r0 = 2 * w, r1 = 2 * w + 1;

#pragma unroll
    for (int k = 1; k <= KT; ++k) {
#pragma unroll
        for (int kf = 0; kf < 4; ++kf) xf[kf] *= tv;   // fold t^k (v_pk_mul_f16)

        const size_t base = ((size_t)(k - 1) * 8) * 4 * 2 * 512;
#pragma unroll
        for (int kf = 0; kf < 4; ++kf) {
            const size_t o0h = base + ((size_t)(r0 * 4 + kf) * 2 + 0) * 512 + l * 8;
            const size_t o0l = base + ((size_t)(r0 * 4 + kf) * 2 + 1) * 512 + l * 8;
            const size_t o1h = base + ((size_t)(r1 * 4 + kf) * 2 + 0) * 512 + l * 8;
            const size_t o1l = base + ((size_t)(r1 * 4 + kf) * 2 + 1) * 512 + l * 8;
            const f16x8 g0h = *reinterpret_cast<const f16x8*>(gws + o0h);
            const f16x8 g0l = *reinterpret_cast<const f16x8*>(gws + o0l);
            const f16x8 g1h = *reinterpret_cast<const f16x8*>(gws + o1h);
            const f16x8 g1l = *reinterpret_cast<const f16x8*>(gws + o1l);
            if (kf < 2) {   // 4 independent accumulator chains (depth 40 each)
                y0a = __builtin_amdgcn_mfma_f32_16x16x32_f16(g0h, xf[kf], y0a, 0, 0, 0);
                y0a = __builtin_amdgcn_mfma_f32_16x16x32_f16(g0l, xf[kf], y0a, 0, 0, 0);
                y1a = __builtin_amdgcn_mfma_f32_16x16x32_f16(g1h, xf[kf], y1a, 0, 0, 0);
                y1a = __builtin_amdgcn_mfma_f32_16x16x32_f16(g1l, xf[kf], y1a, 0, 0, 0);
            } else {
                y0b = __builtin_amdgcn_mfma_f32_16x16x32_f16(g0h, xf[kf], y0b, 0, 0, 0);
                y0b = __builtin_amdgcn_mfma_f32_16x16x32_f16(g0l, xf[kf], y0b, 0, 0, 0);
                y1b = __builtin_amdgcn_mfma_f32_16x16x32_f16(g1h, xf[kf], y1b, 0, 0, 0);
                y1b = __builtin_amdgcn_mfma_f32_16x16x32_f16(g1l, xf[kf], y1b, 0, 0, 0);
            }
        }
    }

    // epilogue: y += bias*t, store
    f32x4 y0 = y0a + y0b;
    f32x4 y1 = y1a + y1b;
    const f32x4 b0 = *reinterpret_cast<const f32x4*>(bias + g0);
    const f32x4 b1 = *reinterpret_cast<const f32x4*>(bias + g0 + 16);
    y0 += b0 * tn;
    y1 += b1 * tn;
    *reinterpret_cast<f32x4*>(out + (size_t)(s0 + n) * DD + g0)      = y0;
    *reinterpret_cast<f32x4*>(out + (size_t)(s0 + n) * DD + g0 + 16) = y1;

    // ljd = diag(W)*t (coalesced: 16 threads cover one sample's 128 dims)
    {
        const int ns = tid >> 4;
        const int dg = (tid & 15) * 8;
        const float ts = t[s0 + ns];
        f32x4 o0, o1;
#pragma unroll
        for (int j = 0; j < 4; ++j) {
            o0[j] = weight[(size_t)(dg + j) * DD + dg + j] * ts;
            o1[j] = weight[(size_t)(dg + 4 + j) * DD + dg + 4 + j] * ts;
        }
        float* lp = out + (size_t)B * DD + (size_t)(s0 + ns) * DD + dg;
        *reinterpret_cast<f32x4*>(lp)     = o0;
        *reinterpret_cast<f32x4*>(lp + 4) = o1;
    }
}

extern "C" void kernel_launch(void* const* d_in, const int* in_sizes, int n_in,
                              void* d_out, int out_size, void* d_ws, size_t ws_size,
                              hipStream_t stream) {
    const float* x      = (const float*)d_in[0];
    const float* t      = (const float*)d_in[1];
    const float* weight = (const float*)d_in[2];
    const float* bias   = (const float*)d_in[3];
    float* out = (float*)d_out;
    _Float16* gws = (_Float16*)d_ws;

    const int B = in_sizes[1];

    gpow_kernel<<<8, 256, 0, stream>>>(weight, gws);
    apply_kernel<<<B / 16, 256, 0, stream>>>(x, t, weight, bias, gws, out, B);
}

// Round 7
// 82.073 us; speedup vs baseline: 1.0593x; 1.0593x over previous
//
#include <hip/hip_runtime.h>

// AffineExponential: y = expm(t*W) @ x + bias*t,  ljd = diag(W)*t
// Taylor action: v_k = (t/k) W v_{k-1}, y = sum v_k, KT=12.
//
// Round-6: fully wave-independent design. 256 blocks x 1 wave; each wave
// owns a 16-sample tile end-to-end: all of W lives in registers as f16
// A-frags (8 row-tiles x 4 k-frags = 128 VGPRs), the per-step C->B layout
// transpose goes through 4.3 KB of wave-private LDS (same-wave DS ordering;
// __syncthreads on a 1-wave block is ~free and only pins compiler order).
// No cross-wave barriers (round-3's skew), no per-block multi-wave startup
// duplication (round-4's regression), no second dispatch (round-5's
// regression). B-frag is pre-scaled by t/k so MFMA output = v_k directly.
// Precision: W,v in f16 (2^-11 rel; beats round-3/4's bf16-v 0.031 absmax).

#define DD 128
#define KT 12
#define KS 136   // vbuf stride in f16 units: keeps ds_read_b128 16B-aligned

typedef float    f32x4 __attribute__((ext_vector_type(4)));
typedef _Float16 f16x8 __attribute__((ext_vector_type(8)));
typedef _Float16 f16x4 __attribute__((ext_vector_type(4)));

__global__ __launch_bounds__(64, 1)
void affine_exp_kernel(const float* __restrict__ x,
                       const float* __restrict__ t,
                       const float* __restrict__ weight,
                       const float* __restrict__ bias,
                       float* __restrict__ out, int B)
{
    __shared__ _Float16 vbuf[16 * KS];   // [col n][kd], wave-private

    const int l  = threadIdx.x;          // 0..63
    const int n  = l & 15;               // MFMA col = sample within tile
    const int q  = l >> 4;               // quad
    const int s0 = blockIdx.x * 16;

    const float tn = t[s0 + n];

    // ---- all of W as f16 A-frags: wf[r][kf] covers rows 16r+[0,16),
    //      kd 32kf+[0,32);  A[m=lane&15][kd=8q+j] ----
    f16x8 wf[8][4];
#pragma unroll
    for (int r = 0; r < 8; ++r)
#pragma unroll
        for (int kf = 0; kf < 4; ++kf) {
            const float* p = weight + (size_t)(16 * r + n) * DD + 32 * kf + 8 * q;
            const f32x4 a = *reinterpret_cast<const f32x4*>(p);
            const f32x4 b = *reinterpret_cast<const f32x4*>(p + 4);
            f16x8 h;
#pragma unroll
            for (int j = 0; j < 4; ++j) {
                h[j]     = (_Float16)a[j];
                h[j + 4] = (_Float16)b[j];
            }
            wf[r][kf] = h;
        }

    // ---- v_0 = x as (unscaled) B-frags: B[kd=32kf+8q+j][col n] ----
    f16x8 vraw[4];
    {
        const float* xp = x + (size_t)(s0 + n) * DD + 8 * q;
#pragma unroll
        for (int kf = 0; kf < 4; ++kf) {
            const f32x4 a = *reinterpret_cast<const f32x4*>(xp + 32 * kf);
            const f32x4 b = *reinterpret_cast<const f32x4*>(xp + 32 * kf + 4);
            f16x8 h;
#pragma unroll
            for (int j = 0; j < 4; ++j) {
                h[j]     = (_Float16)a[j];
                h[j + 4] = (_Float16)b[j];
            }
            vraw[kf] = h;
        }
    }

    // ---- y init = x (k=0 term) in C-layout: col n, row tile r: 16r+4q+jr ----
    f32x4 y[8];
#pragma unroll
    for (int r = 0; r < 8; ++r)
        y[r] = *reinterpret_cast<const f32x4*>(x + (size_t)(s0 + n) * DD + 16 * r + 4 * q);

    // ---- Taylor loop, fully wave-private ----
#pragma unroll
    for (int k = 1; k <= KT; ++k) {
        const float c = tn * (1.0f / (float)k);
        const _Float16 ch = (_Float16)c;
        f16x8 cv;
#pragma unroll
        for (int j = 0; j < 8; ++j) cv[j] = ch;

        f16x8 vb[4];
#pragma unroll
        for (int kf = 0; kf < 4; ++kf) vb[kf] = vraw[kf] * cv;   // fold t/k

        f32x4 acc[8];
#pragma unroll
        for (int r = 0; r < 8; ++r) acc[r] = (f32x4){0.f, 0.f, 0.f, 0.f};

        // 32 MFMAs = 8 independent chains of depth 4
#pragma unroll
        for (int kf = 0; kf < 4; ++kf)
#pragma unroll
            for (int r = 0; r < 8; ++r)
                acc[r] = __builtin_amdgcn_mfma_f32_16x16x32_f16(wf[r][kf], vb[kf], acc[r], 0, 0, 0);

#pragma unroll
        for (int r = 0; r < 8; ++r) y[r] += acc[r];   // acc == v_k (pre-scaled B)

        if (k < KT) {
            // C-layout -> B-layout transpose through wave-private LDS
#pragma unroll
            for (int r = 0; r < 8; ++r) {
                f16x4 pk;
#pragma unroll
                for (int jr = 0; jr < 4; ++jr) pk[jr] = (_Float16)acc[r][jr];
                *reinterpret_cast<f16x4*>(&vbuf[n * KS + 16 * r + 4 * q]) = pk;
            }
            __syncthreads();   // 1-wave block: ~free; pins LDS write->read order
#pragma unroll
            for (int kf = 0; kf < 4; ++kf)
                vraw[kf] = *reinterpret_cast<const f16x8*>(&vbuf[n * KS + 32 * kf + 8 * q]);
        }
    }

    // ---- epilogue: y += bias*t, store ----
#pragma unroll
    for (int r = 0; r < 8; ++r) {
        const f32x4 bv = *reinterpret_cast<const f32x4*>(bias + 16 * r + 4 * q);
        const f32x4 o  = y[r] + bv * tn;
        *reinterpret_cast<f32x4*>(out + (size_t)(s0 + n) * DD + 16 * r + 4 * q) = o;
    }

    // ---- ljd = diag(W)*t: lane owns dims {2l, 2l+1}, loop 16 samples ----
    {
        const float d0 = weight[(size_t)(2 * l) * DD + 2 * l];
        const float d1 = weight[(size_t)(2 * l + 1) * DD + 2 * l + 1];
        float* lout = out + (size_t)B * DD;
#pragma unroll
        for (int j = 0; j < 16; ++j) {
            const float tj = t[s0 + j];
            *reinterpret_cast<float2*>(lout + (size_t)(s0 + j) * DD + 2 * l) =
                make_float2(d0 * tj, d1 * tj);
        }
    }
}

extern "C" void kernel_launch(void* const* d_in, const int* in_sizes, int n_in,
                              void* d_out, int out_size, void* d_ws, size_t ws_size,
                              hipStream_t stream) {
    const float* x      = (const float*)d_in[0];
    const float* t      = (const float*)d_in[1];
    const float* weight = (const float*)d_in[2];
    const float* bias   = (const float*)d_in[3];
    float* out = (float*)d_out;

    const int B = in_sizes[1];            // one scalar t per sample
    const int blocks = B / 16;            // 4096/16 = 256 -> one wave per CU

    affine_exp_kernel<<<blocks, 64, 0, stream>>>(x, t, weight, bias, out, B);
}

// Round 8
// 69.647 us; speedup vs baseline: 1.2483x; 1.1784x over previous
//
#include <hip/hip_runtime.h>

// AffineExponential: y = expm(t*W) @ x + bias*t,  ljd = diag(W)*t
// Taylor action: v_k = (t/k) W v_{k-1}, y = sum v_k, KT=12, all f16 MFMA.
//
// Round-7: round 6 (same design) hit the 256-VGPR cap and SPILLED —
// WRITE_SIZE 15.4 MB vs 4.2 ideal, FETCH 6.0 vs 2.5 = scratch traffic, 48.6us.
// Fixes: acc[8]->acc[4] (row-tiles in 2 groups), no pre-scaled B copy (scale
// MFMA output instead; kills vb[4]), #pragma unroll 1 on the k-loop (no
// cross-iteration live-range inflation). Live set ~210 VGPR: wf 128 + y 32
// + vraw 16 + acc 16 + temps. vbuf re-laid out so ds_read_b128 is the
// canonical lane*16B conflict-free pattern.

#define DD 128
#define KT 12

typedef float    f32x4 __attribute__((ext_vector_type(4)));
typedef _Float16 f16x8 __attribute__((ext_vector_type(8)));
typedef _Float16 f16x4 __attribute__((ext_vector_type(4)));

__global__ __launch_bounds__(64, 1)
void affine_exp_kernel(const float* __restrict__ x,
                       const float* __restrict__ t,
                       const float* __restrict__ weight,
                       const float* __restrict__ bias,
                       float* __restrict__ out, int B)
{
    // vbuf: 4 kf-blocks of 512 halves; lane l's B-frag chunk at kf*512 + l*8
    // (canonical conflict-free ds_read_b128). 4 KB total, wave-private.
    __shared__ _Float16 vbuf[4 * 512];

    const int l  = threadIdx.x;          // 0..63
    const int n  = l & 15;               // MFMA col = sample within tile
    const int q  = l >> 4;               // quad
    const int s0 = blockIdx.x * 16;

    const float tn = t[s0 + n];

    // ---- all of W as f16 A-frags: wf[r][kf] = rows 16r+[0,16), kd 32kf+[0,32)
    //      A[m=16r+n][kd=32kf+8q+j]  (4 q-lanes cover one 128B line per row)
    f16x8 wf[8][4];
#pragma unroll
    for (int r = 0; r < 8; ++r)
#pragma unroll
        for (int kf = 0; kf < 4; ++kf) {
            const float* p = weight + (size_t)(16 * r + n) * DD + 32 * kf + 8 * q;
            const f32x4 a = *reinterpret_cast<const f32x4*>(p);
            const f32x4 b = *reinterpret_cast<const f32x4*>(p + 4);
            f16x8 h;
#pragma unroll
            for (int j = 0; j < 4; ++j) {
                h[j]     = (_Float16)a[j];
                h[j + 4] = (_Float16)b[j];
            }
            wf[r][kf] = h;
        }

    // ---- v_0 = x as f16 B-frags: B[kd=32kf+8q+j][col n] ----
    f16x8 vraw[4];
    const float* xp = x + (size_t)(s0 + n) * DD;
#pragma unroll
    for (int kf = 0; kf < 4; ++kf) {
        const f32x4 a = *reinterpret_cast<const f32x4*>(xp + 32 * kf + 8 * q);
        const f32x4 b = *reinterpret_cast<const f32x4*>(xp + 32 * kf + 8 * q + 4);
        f16x8 h;
#pragma unroll
        for (int j = 0; j < 4; ++j) {
            h[j]     = (_Float16)a[j];
            h[j + 4] = (_Float16)b[j];
        }
        vraw[kf] = h;
    }

    // ---- y init = x (k=0 term), C-layout: col n, rows 16r+4q+[0,4) ----
    f32x4 y[8];
#pragma unroll
    for (int r = 0; r < 8; ++r)
        y[r] = *reinterpret_cast<const f32x4*>(xp + 16 * r + 4 * q);

    // ---- Taylor recurrence, wave-private, 2 row-groups to cap registers ----
#pragma unroll 1
    for (int k = 1; k <= KT; ++k) {
        const float c = tn * (1.0f / (float)k);
#pragma unroll
        for (int g = 0; g < 2; ++g) {
            f32x4 acc[4];
#pragma unroll
            for (int rr = 0; rr < 4; ++rr) acc[rr] = (f32x4){0.f, 0.f, 0.f, 0.f};
            // 16 MFMAs = 4 independent chains of depth 4
#pragma unroll
            for (int kf = 0; kf < 4; ++kf)
#pragma unroll
                for (int rr = 0; rr < 4; ++rr)
                    acc[rr] = __builtin_amdgcn_mfma_f32_16x16x32_f16(
                        wf[g * 4 + rr][kf], vraw[kf], acc[rr], 0, 0, 0);
#pragma unroll
            for (int rr = 0; rr < 4; ++rr) {
                const int r = g * 4 + rr;
                const f32x4 vk = acc[rr] * c;     // v_k rows 16r+4q+[0,4), col n
                y[r] += vk;
                if (k < KT) {
                    f16x4 pk;
#pragma unroll
                    for (int jr = 0; jr < 4; ++jr) pk[jr] = (_Float16)vk[jr];
                    const int kd0  = 16 * r + 4 * q;
                    const int addr = (kd0 >> 5) * 512 + (n + 16 * ((kd0 & 31) >> 3)) * 8 + (kd0 & 7);
                    *reinterpret_cast<f16x4*>(&vbuf[addr]) = pk;
                }
            }
        }
        if (k < KT) {
            __syncthreads();   // 1-wave block: ~free; pins LDS write->read order
#pragma unroll
            for (int kf = 0; kf < 4; ++kf)
                vraw[kf] = *reinterpret_cast<const f16x8*>(&vbuf[kf * 512 + l * 8]);
        }
    }

    // ---- epilogue: y += bias*t, store ----
#pragma unroll
    for (int r = 0; r < 8; ++r) {
        const f32x4 bv = *reinterpret_cast<const f32x4*>(bias + 16 * r + 4 * q);
        const f32x4 o  = y[r] + bv * tn;
        *reinterpret_cast<f32x4*>(out + (size_t)(s0 + n) * DD + 16 * r + 4 * q) = o;
    }

    // ---- ljd = diag(W)*t: lane owns dims {2l, 2l+1}; coalesced 8B stores ----
    {
        const float d0 = weight[(size_t)(2 * l) * DD + 2 * l];
        const float d1 = weight[(size_t)(2 * l + 1) * DD + 2 * l + 1];
        float* lout = out + (size_t)B * DD;
#pragma unroll
        for (int j = 0; j < 16; ++j) {
            const float tj = t[s0 + j];
            *reinterpret_cast<float2*>(lout + (size_t)(s0 + j) * DD + 2 * l) =
                make_float2(d0 * tj, d1 * tj);
        }
    }
}

extern "C" void kernel_launch(void* const* d_in, const int* in_sizes, int n_in,
                              void* d_out, int out_size, void* d_ws, size_t ws_size,
                              hipStream_t stream) {
    const float* x      = (const float*)d_in[0];
    const float* t      = (const float*)d_in[1];
    const float* weight = (const float*)d_in[2];
    const float* bias   = (const float*)d_in[3];
    float* out = (float*)d_out;

    const int B = in_sizes[1];            // one scalar t per sample
    const int blocks = B / 16;            // 4096/16 = 256 -> one wave per CU

    affine_exp_kernel<<<blocks, 64, 0, stream>>>(x, t, weight, bias, out, B);
}